// Round 7
// baseline (100.153 us; speedup 1.0000x reference)
//
#include <hip/hip_runtime.h>
#include <math.h>

#define B 2
#define C 64
#define N 4096
#define O3 384
#define HID 128
#define NH 4
#define DH 32
#define JC 64
#define NCH (N / JC)   /* 64 */
#define PB 64

#define SCALE 0.17677669529663687f /* 32^-0.5 */

// ---------------- K0: per-position RMS scale ----------------
// grid: 64 blocks x 128 thr. scale[b*N+p] = 8 / max(||x[:,p]||, eps)
__global__ __launch_bounds__(128) void k0_scale(
    const float* __restrict__ x, float* __restrict__ scale)
{
    const int bx = blockIdx.x;
    const int b = bx >> 5;
    const int p = (bx & 31) * 128 + threadIdx.x;
    const float* xb = x + (size_t)b * C * N + p;
    float s = 0.f;
    #pragma unroll 8
    for (int c = 0; c < C; ++c) {
        float v = xb[(size_t)c * N];
        s += v * v;
    }
    scale[(size_t)b * N + p] = 8.0f / fmaxf(sqrtf(s), 1e-12f);
}

// ---------------- K1: QKV projection (norm pre-folded at staging) ----------------
// grid: 12 o-blocks x 128 pos-blocks = 1536 blocks of 256.
// Block: 64 positions x 32 outputs. Thread: 1 position x 8 outputs.
__global__ __launch_bounds__(256) void k1_qkv(
    const float* __restrict__ x, const float* __restrict__ g,
    const float* __restrict__ scale, const float* __restrict__ wqkv,
    float* __restrict__ qkv)
{
    __shared__ float xs[C][68];

    const int t = threadIdx.x;
    const int bx = blockIdx.x;
    const int ob = bx / 128;
    const int pblk = bx % 128;
    const int b = pblk >> 6;
    const int p0 = (pblk & 63) * PB;

    const float* xb = x + (size_t)b * C * N + p0;
    const float* scb = scale + (size_t)b * N + p0;
    #pragma unroll
    for (int it = 0; it < 4; ++it) {
        int idx = t + it * 256;              /* 1024 float4 = 64 rows x 16 */
        int row = idx >> 4, c4 = (idx & 15) * 4;
        float4 v4 = *(const float4*)(xb + (size_t)row * N + c4);
        float4 s4 = *(const float4*)(scb + c4);
        float gv = g[row];
        xs[row][c4 + 0] = v4.x * gv * s4.x;
        xs[row][c4 + 1] = v4.y * gv * s4.y;
        xs[row][c4 + 2] = v4.z * gv * s4.z;
        xs[row][c4 + 3] = v4.w * gv * s4.w;
    }
    __syncthreads();

    const int p = t & 63;
    const int og = __builtin_amdgcn_readfirstlane(t >> 6); /* 0..3 */
    const int obase = ob * 32 + og * 8;
    float acc[8] = {0,0,0,0,0,0,0,0};
    #pragma unroll
    for (int c4 = 0; c4 < 16; ++c4) {
        const float xv0 = xs[c4 * 4 + 0][p];
        const float xv1 = xs[c4 * 4 + 1][p];
        const float xv2 = xs[c4 * 4 + 2][p];
        const float xv3 = xs[c4 * 4 + 3][p];
        #pragma unroll
        for (int k = 0; k < 8; ++k) {
            const float4 w4 = *(const float4*)(wqkv + (size_t)(obase + k) * C + c4 * 4);
            acc[k] += w4.x * xv0 + w4.y * xv1 + w4.z * xv2 + w4.w * xv3;
        }
    }
    const float qs = (obase < HID) ? SCALE : 1.0f;
    float* outb = qkv + (size_t)b * O3 * N + p0 + p;
    #pragma unroll
    for (int k = 0; k < 8; ++k)
        outb[(size_t)(obase + k) * N] = acc[k] * qs;
}

// ---------------- K2: partial M = K V^T per (b, h, j-chunk) ----------------
// grid: B*NH*NCH = 512 blocks of 256. Thread t -> M[e][d0..d0+3].
__global__ __launch_bounds__(256) void k2_kv_outer(
    const float* __restrict__ qkv, float* __restrict__ mpart)
{
    __shared__ float ks[DH][JC + 4];
    __shared__ float vs[DH][JC + 4];
    const int t = threadIdx.x;
    const int bx = blockIdx.x;
    const int b = bx / (NH * NCH);
    const int rem = bx % (NH * NCH);
    const int h = rem / NCH, ch = rem % NCH;
    const int j0 = ch * JC;

    const float* kb = qkv + (size_t)b * O3 * N + (size_t)(HID + h * DH) * N + j0;
    const float* vb = qkv + (size_t)b * O3 * N + (size_t)(2 * HID + h * DH) * N + j0;
    #pragma unroll
    for (int it = 0; it < 2; ++it) {         /* 512 float4 per tensor */
        int idx = t + it * 256;
        int row = idx >> 4, c4 = (idx & 15) * 4;
        *(float4*)&ks[row][c4] = *(const float4*)(kb + (size_t)row * N + c4);
        *(float4*)&vs[row][c4] = *(const float4*)(vb + (size_t)row * N + c4);
    }
    __syncthreads();

    const int e = t >> 3, d0 = (t & 7) * 4;
    float a0 = 0, a1 = 0, a2 = 0, a3 = 0;
    #pragma unroll
    for (int j4 = 0; j4 < JC / 4; ++j4) {
        const float4 kk = *(const float4*)&ks[e][j4 * 4];
        const float4 v0 = *(const float4*)&vs[d0 + 0][j4 * 4];
        const float4 v1 = *(const float4*)&vs[d0 + 1][j4 * 4];
        const float4 v2 = *(const float4*)&vs[d0 + 2][j4 * 4];
        const float4 v3 = *(const float4*)&vs[d0 + 3][j4 * 4];
        a0 += kk.x * v0.x + kk.y * v0.y + kk.z * v0.z + kk.w * v0.w;
        a1 += kk.x * v1.x + kk.y * v1.y + kk.z * v1.z + kk.w * v1.w;
        a2 += kk.x * v2.x + kk.y * v2.y + kk.z * v2.z + kk.w * v2.w;
        a3 += kk.x * v3.x + kk.y * v3.y + kk.z * v3.z + kk.w * v3.w;
    }
    ((float4*)(mpart + (size_t)((b * NH + h) * NCH + ch) * 1024))[t] =
        make_float4(a0, a1, a2, a3);
}

// ---------------- K2b: reduce M partials + fold w_out -> U ----------------
// grid: B*NH*4 = 32 blocks of 256 (e-quarters, 8 e-rows each).
__global__ __launch_bounds__(256) void k2b_fold_u(
    const float* __restrict__ mpart, const float* __restrict__ wout,
    float* __restrict__ U)
{
    __shared__ float Ms[8][DH + 1];
    const int t = threadIdx.x;
    const int bx = blockIdx.x;
    const int eq = bx & 3;
    const int bh = bx >> 2;
    const int b = bh / NH, h = bh % NH;

    const float* mp = mpart + (size_t)bh * NCH * 1024 + eq * 256;
    float acc = 0.f;
    #pragma unroll 8
    for (int ch = 0; ch < NCH; ++ch)
        acc += mp[(size_t)ch * 1024 + t];
    Ms[t >> 5][t & 31] = acc;
    __syncthreads();

    #pragma unroll
    for (int half = 0; half < 2; ++half) {
        int u = t + half * 256;              /* o = u&63, er = u>>6 */
        int o = u & 63, er = u >> 6;
        float s = 0.f;
        #pragma unroll
        for (int d4 = 0; d4 < 8; ++d4) {
            const float4 w4 = *(const float4*)(wout + (size_t)o * HID + h * DH + d4 * 4);
            s += w4.x * Ms[er][d4 * 4 + 0] + w4.y * Ms[er][d4 * 4 + 1]
               + w4.z * Ms[er][d4 * 4 + 2] + w4.w * Ms[er][d4 * 4 + 3];
        }
        U[((size_t)b * C + o) * HID + h * DH + eq * 8 + er] = s;
    }
}

// ---------------- K3: out = U @ q + b_out + x ----------------
// grid: 8 o-blocks x 128 pos-blocks = 1024 blocks of 256.
// Block: 64 positions x 8 outputs. Thread: 1 position x 2 outputs.
__global__ __launch_bounds__(256) void k3_final(
    const float* __restrict__ qkv, const float* __restrict__ U,
    const float* __restrict__ bout, const float* __restrict__ x,
    float* __restrict__ out)
{
    __shared__ float qs[HID][68];
    const int t = threadIdx.x;
    const int bx = blockIdx.x;
    const int ob = bx >> 7;                  /* 0..7: 8 outputs each */
    const int pblk = bx & 127;
    const int b = pblk >> 6;
    const int p0 = (pblk & 63) * PB;

    const float* qb = qkv + (size_t)b * O3 * N + p0;
    #pragma unroll
    for (int it = 0; it < 8; ++it) {         /* 2048 float4 = 128 rows x 16 */
        int idx = t + it * 256;
        int row = idx >> 4, c4 = (idx & 15) * 4;
        *(float4*)&qs[row][c4] = *(const float4*)(qb + (size_t)row * N + c4);
    }
    __syncthreads();

    const int p = t & 63;
    const int og = __builtin_amdgcn_readfirstlane(t >> 6); /* 0..3 */
    const int o0 = ob * 8 + og * 2;
    const float* Ub = U + ((size_t)b * C + o0) * HID;
    float a0 = bout[o0], a1 = bout[o0 + 1];
    #pragma unroll
    for (int c4 = 0; c4 < 32; ++c4) {
        const float q0 = qs[c4 * 4 + 0][p];
        const float q1 = qs[c4 * 4 + 1][p];
        const float q2 = qs[c4 * 4 + 2][p];
        const float q3 = qs[c4 * 4 + 3][p];
        const float4 u0 = *(const float4*)(Ub + 0 * HID + c4 * 4);
        const float4 u1 = *(const float4*)(Ub + 1 * HID + c4 * 4);
        a0 += u0.x * q0 + u0.y * q1 + u0.z * q2 + u0.w * q3;
        a1 += u1.x * q0 + u1.y * q1 + u1.z * q2 + u1.w * q3;
    }
    const float* xb = x + ((size_t)b * C + o0) * N + p0 + p;
    float* ob_ = out + ((size_t)b * C + o0) * N + p0 + p;
    ob_[0] = a0 + xb[0];
    ob_[(size_t)N] = a1 + xb[(size_t)N];
}

extern "C" void kernel_launch(void* const* d_in, const int* in_sizes, int n_in,
                              void* d_out, int out_size, void* d_ws, size_t ws_size,
                              hipStream_t stream)
{
    const float* x    = (const float*)d_in[0];
    const float* g    = (const float*)d_in[1];
    const float* wqkv = (const float*)d_in[2];
    const float* wout = (const float*)d_in[3];
    const float* bout = (const float*)d_in[4];
    float* out = (float*)d_out;

    float* qkv   = (float*)d_ws;                        /* 12.58 MB */
    float* mpart = qkv + (size_t)B * O3 * N;            /* 2.10 MB  */
    float* U     = mpart + (size_t)B * NH * NCH * 1024; /* 65 KB    */
    float* scale = U + (size_t)B * C * HID;             /* 32 KB    */

    k0_scale<<<64, 128, 0, stream>>>(x, scale);
    k1_qkv<<<12 * 128, 256, 0, stream>>>(x, g, scale, wqkv, qkv);
    k2_kv_outer<<<B * NH * NCH, 256, 0, stream>>>(qkv, mpart);
    k2b_fold_u<<<B * NH * 4, 256, 0, stream>>>(mpart, wout, U);
    k3_final<<<8 * 128, 256, 0, stream>>>(qkv, U, bout, x, out);
}